// Round 3
// baseline (163.006 us; speedup 1.0000x reference)
//
#include <hip/hip_runtime.h>
#include <stdint.h>

// out[h,k,v] = 0.95*M[h,k,v] + sum_{b,s} rho[b,s]*K[b,s,h,k]*V[b,s,h,v]
// B=4, S=4096 (ROWS=16384), H=16, Dk=Dv=64.
//
// R9: kill the atomic epilogue + deepen prefetch.
// R6 and R8 (totally different load/compute structures) both measured 51.5us
// with VALUBusy<4%, MfmaUtil<2%, HBM 20% -> bound by what they SHARE:
//   (a) 4.2M fp32 atomicAdds into 256KB: WRITE_SIZE=16.8MB per dispatch =
//       4.2M x 4B write-through RMW transactions -- a serialized end-of-kernel
//       storm (out is only 256KB).
//   (b) per-round vmcnt stall: loads issued ~150cy before use vs ~600-900cy
//       HBM latency, all waves stalled at the same barrier.
// Fixes:
//   (a) two-stage: accum -> plain streaming stores of per-(slice,head) 64x64
//       partials into d_ws (16MiB); reduce_ws: out = 0.95*mem + sum(ws).
//       Host falls back to the proven R8 atomic path if ws_size < 16MiB.
//   (b) 2-round-deep register prefetch: loadr(r+2) issued during round r,
//       writer(r+1) consumes loads issued a full round earlier.
// Compute core (verified R8, absmax 2.0): subtiled [s/4][c/16][4][16] bf16
// LDS tiles, ds_read_b64_tr_b16 fragments (column in addr bits [6:3]),
// mfma_f32_16x16x32_bf16, waves own disjoint 32x32 output quadrants.

typedef __bf16  bf16x8  __attribute__((ext_vector_type(8)));
typedef __bf16  bf16x4  __attribute__((ext_vector_type(4)));
typedef short   s16x4   __attribute__((ext_vector_type(4)));
typedef float   floatx4 __attribute__((ext_vector_type(4)));

constexpr int HH   = 16;
constexpr int DK   = 64;
constexpr int DV   = 64;
constexpr int ROWS = 16384;
constexpr int NSLICE = 64;
constexpr int RPB  = ROWS / NSLICE;   // 256 rows per block
constexpr int TR   = 32;              // s-rows staged per round
constexpr int NR   = RPB / TR;        // 8 rounds
constexpr float DECAY = 0.95f;
constexpr size_t WS_NEED = (size_t)NSLICE * HH * DK * DV * sizeof(float); // 16 MiB

__global__ __launch_bounds__(256) void init_out(const float* __restrict__ mem,
                                                float* __restrict__ out) {
    int i = blockIdx.x * 256 + threadIdx.x;
    out[i] = DECAY * mem[i];
}

__device__ __forceinline__ unsigned lds_off(const void* p) {
    return (unsigned)(uintptr_t)(__attribute__((address_space(3))) const void*)p;
}

template <bool TWOSTAGE>
__global__ __launch_bounds__(256, 4) void accum(const float* __restrict__ keys,
                                                const float* __restrict__ values,
                                                const float* __restrict__ rho,
                                                float* __restrict__ dst) {
    __shared__ __align__(128) __bf16 kb[2][TR * DK];   // 8 KiB
    __shared__ __align__(128) __bf16 vb[2][TR * DV];   // 8 KiB
    __shared__ float rs[RPB];                          // 1 KiB

    const int t    = threadIdx.x;
    const int lane = t & 63;
    const int w    = t >> 6;
    const int wr   = w >> 1;          // output-row quadrant (Dk)
    const int wc   = w & 1;           // output-col quadrant (Dv)
    const int m    = lane & 15;
    const int q    = lane >> 4;
    const int h    = blockIdx.y;
    const int row0 = blockIdx.x * RPB;

    rs[t] = rho[row0 + t];            // whole block's rho, once

    const int sl0 = t >> 4;           // 0..15 (+16 for second half)
    const int c0  = (t & 15) * 4;

    float4 pk[2][2], pv[2][2];        // [set][half]

    auto loadr = [&](int r, int set) {
        #pragma unroll
        for (int i = 0; i < 2; ++i) {
            const int sl = sl0 + i * 16;
            const size_t off = ((size_t)(row0 + r * TR + sl) * HH + h) * DK + c0;
            pk[set][i] = *(const float4*)(keys + off);
            pv[set][i] = *(const float4*)(values + off);
        }
    };
    auto writer = [&](int r, int set, int b) {
        #pragma unroll
        for (int i = 0; i < 2; ++i) {
            const int sl = sl0 + i * 16;
            const float rv = rs[r * TR + sl];
            bf16x4 kh = {(__bf16)(pk[set][i].x * rv), (__bf16)(pk[set][i].y * rv),
                         (__bf16)(pk[set][i].z * rv), (__bf16)(pk[set][i].w * rv)};
            bf16x4 vh = {(__bf16)pv[set][i].x, (__bf16)pv[set][i].y,
                         (__bf16)pv[set][i].z, (__bf16)pv[set][i].w};
            // subtiled: elem(sl,c) at ((sl>>2)*4 + c>>4)*64 + (sl&3)*16 + (c&15)
            const int eo = ((sl >> 2) * 4 + (c0 >> 4)) * 64 + (sl & 3) * 16 + (c0 & 15);
            *(bf16x4*)&kb[b][eo] = kh;
            *(bf16x4*)&vb[b][eo] = vh;
        }
    };

    floatx4 acc[2][2];
    #pragma unroll
    for (int i = 0; i < 2; ++i)
        #pragma unroll
        for (int j = 0; j < 2; ++j)
            acc[i][j] = (floatx4){0.f, 0.f, 0.f, 0.f};

    loadr(0, 0);
    loadr(1, 1);
    __syncthreads();                  // rs visible
    writer(0, 0, 0);

    for (int r = 0; r < NR; ++r) {
        const int cur = r & 1;
        __syncthreads();              // buf[cur] staged; prior reads of buf[cur^1] done

        // A-frag elem j = Kscaled[q*8+j][wr*32 + mt*16 + m]
        // tr-read: 128B subtile base + 8*m (column in addr bits [6:3]); j>=4 at +512B
        const unsigned abase = lds_off(&kb[cur][0]) + q * 1024 + 8 * m;
        const unsigned bbase = lds_off(&vb[cur][0]) + q * 1024 + 8 * m;

        s16x4 alo[2], ahi[2], blo[2], bhi[2];
        #pragma unroll
        for (int mt = 0; mt < 2; ++mt) {
            const unsigned ad = abase + (unsigned)((wr * 2 + mt) * 128);
            asm volatile("ds_read_b64_tr_b16 %0, %1" : "=v"(alo[mt]) : "v"(ad));
            asm volatile("ds_read_b64_tr_b16 %0, %1 offset:512" : "=v"(ahi[mt]) : "v"(ad));
        }
        #pragma unroll
        for (int nt = 0; nt < 2; ++nt) {
            const unsigned bd = bbase + (unsigned)((wc * 2 + nt) * 128);
            asm volatile("ds_read_b64_tr_b16 %0, %1" : "=v"(blo[nt]) : "v"(bd));
            asm volatile("ds_read_b64_tr_b16 %0, %1 offset:512" : "=v"(bhi[nt]) : "v"(bd));
        }

        if (r + 2 < NR) loadr(r + 2, cur);   // issue globals 2 rounds ahead

        asm volatile("s_waitcnt lgkmcnt(0)" ::: "memory");
        __builtin_amdgcn_sched_barrier(0);   // rule 18

        bf16x8 af[2], bfv[2];
        #pragma unroll
        for (int mt = 0; mt < 2; ++mt) {
            union { s16x4 hh[2]; bf16x8 v; } u;
            u.hh[0] = alo[mt]; u.hh[1] = ahi[mt];
            af[mt] = u.v;
        }
        #pragma unroll
        for (int nt = 0; nt < 2; ++nt) {
            union { s16x4 hh[2]; bf16x8 v; } u;
            u.hh[0] = blo[nt]; u.hh[1] = bhi[nt];
            bfv[nt] = u.v;
        }

        #pragma unroll
        for (int mt = 0; mt < 2; ++mt)
            #pragma unroll
            for (int nt = 0; nt < 2; ++nt)
                acc[mt][nt] = __builtin_amdgcn_mfma_f32_16x16x32_bf16(
                    af[mt], bfv[nt], acc[mt][nt], 0, 0, 0);

        if (r + 1 < NR) writer(r + 1, (r + 1) & 1, (r + 1) & 1);  // loads from round r-1
    }

    // epilogue — C/D: [row = mt*16 + q*4 + g][col = nt*16 + m]  (verified R6/R8)
    if (TWOSTAGE) {
        // plain streaming stores of this block's 64x64 partial into ws
        float* o = dst + ((size_t)(blockIdx.x * HH + h)) * (DK * DV)
                       + (wr * 32) * DV + wc * 32;
        #pragma unroll
        for (int mt = 0; mt < 2; ++mt)
            #pragma unroll
            for (int nt = 0; nt < 2; ++nt)
                #pragma unroll
                for (int g = 0; g < 4; ++g)
                    o[(mt * 16 + q * 4 + g) * DV + nt * 16 + m] = acc[mt][nt][g];
    } else {
        float* o = dst + h * (DK * DV) + (wr * 32) * DV + wc * 32;
        #pragma unroll
        for (int mt = 0; mt < 2; ++mt)
            #pragma unroll
            for (int nt = 0; nt < 2; ++nt)
                #pragma unroll
                for (int g = 0; g < 4; ++g)
                    atomicAdd(o + (mt * 16 + q * 4 + g) * DV + nt * 16 + m,
                              acc[mt][nt][g]);
    }
}

// out = 0.95*mem + sum over 64 slice-partials. 64 blocks x 256 threads,
// one float4 per thread; reads are coalesced within each 256KB slice slab.
__global__ __launch_bounds__(256) void reduce_ws(const float* __restrict__ mem,
                                                 const float* __restrict__ ws,
                                                 float* __restrict__ out) {
    const int i4 = blockIdx.x * 256 + threadIdx.x;    // 0..16383
    const floatx4* wv = (const floatx4*)ws;
    constexpr int SLAB = HH * DK * DV / 4;            // 16384 float4 per slice
    floatx4 s0 = {0.f, 0.f, 0.f, 0.f}, s1 = {0.f, 0.f, 0.f, 0.f};
    #pragma unroll 8
    for (int sl = 0; sl < NSLICE; sl += 2) {
        s0 += wv[(size_t)sl * SLAB + i4];
        s1 += wv[(size_t)(sl + 1) * SLAB + i4];
    }
    const floatx4 m4 = ((const floatx4*)mem)[i4];
    ((floatx4*)out)[i4] = DECAY * m4 + (s0 + s1);
}

extern "C" void kernel_launch(void* const* d_in, const int* in_sizes, int n_in,
                              void* d_out, int out_size, void* d_ws, size_t ws_size,
                              hipStream_t stream) {
    const float* mem    = (const float*)d_in[0];  // (H, Dk, Dv)
    const float* keys   = (const float*)d_in[1];  // (B, S, H, Dk)
    const float* values = (const float*)d_in[2];  // (B, S, H, Dv)
    const float* rho    = (const float*)d_in[3];  // (B, S)
    float* out = (float*)d_out;                   // (H, Dk, Dv)

    dim3 grid(NSLICE, HH);
    if (ws_size >= WS_NEED) {
        accum<true><<<grid, dim3(256), 0, stream>>>(keys, values, rho, (float*)d_ws);
        reduce_ws<<<dim3(HH * DK * DV / 4 / 256), dim3(256), 0, stream>>>(
            mem, (const float*)d_ws, out);
    } else {
        init_out<<<dim3((HH * DK * DV) / 256), dim3(256), 0, stream>>>(mem, out);
        accum<false><<<grid, dim3(256), 0, stream>>>(keys, values, rho, out);
    }
}